// Round 16
// baseline (181.381 us; speedup 1.0000x reference)
//
#include <hip/hip_runtime.h>

typedef __attribute__((ext_vector_type(8))) short s8bf;     // 8 bf16 payload
typedef __attribute__((ext_vector_type(8))) __bf16 v8bf;    // MFMA operand type
typedef __attribute__((ext_vector_type(4))) float f32x4;

__device__ __forceinline__ short f2bf(float f) {
  union { float f; unsigned u; } v; v.f = f;
  unsigned r = v.u + 0x7FFFu + ((v.u >> 16) & 1u);  // RNE
  return (short)(r >> 16);
}

__device__ __forceinline__ s8bf pack8v(f32x4 a, f32x4 b) {
  s8bf o;
  o[0] = f2bf(a[0]); o[1] = f2bf(a[1]); o[2] = f2bf(a[2]); o[3] = f2bf(a[3]);
  o[4] = f2bf(b[0]); o[5] = f2bf(b[1]); o[6] = f2bf(b[2]); o[7] = f2bf(b[3]);
  return o;
}

__device__ __forceinline__ f32x4 mfma16(s8bf a, s8bf b, f32x4 c) {
  return __builtin_amdgcn_mfma_f32_16x16x32_bf16(
      __builtin_bit_cast(v8bf, a), __builtin_bit_cast(v8bf, b), c, 0, 0, 0);
}

__device__ __forceinline__ void gl_lds16(const void* g, void* l) {
  __builtin_amdgcn_global_load_lds(
      (const __attribute__((address_space(1))) unsigned*)g,
      (__attribute__((address_space(3))) unsigned*)l, 16, 0, 0);
}

// ======== cast kernel: f32 -> bf16, nontemporal streaming, 16B stores ========
__global__ __launch_bounds__(256) void cast_k(
    const float* __restrict__ x, const float* __restrict__ ctx,
    const void* __restrict__ msk,
    short* __restrict__ xbf, short* __restrict__ ctxbf, float* __restrict__ bias)
{
  __shared__ int fmt;
  const int blk = blockIdx.x;
  const int t = threadIdx.x;
  if (blk < 1664) {
    const f32x4* src;
    s8bf* dst;
    if (blk < 1536) { src = (const f32x4*)x + (size_t)blk * 2048;
                      dst = (s8bf*)xbf + (size_t)blk * 1024; }
    else            { src = (const f32x4*)ctx + (size_t)(blk - 1536) * 2048;
                      dst = (s8bf*)ctxbf + (size_t)(blk - 1536) * 1024; }
    f32x4 a0 = __builtin_nontemporal_load(src + 2 * t);
    f32x4 b0 = __builtin_nontemporal_load(src + 2 * t + 1);
    f32x4 a1 = __builtin_nontemporal_load(src + 2 * t + 512);
    f32x4 b1 = __builtin_nontemporal_load(src + 2 * t + 513);
    f32x4 a2 = __builtin_nontemporal_load(src + 2 * t + 1024);
    f32x4 b2 = __builtin_nontemporal_load(src + 2 * t + 1025);
    f32x4 a3 = __builtin_nontemporal_load(src + 2 * t + 1536);
    f32x4 b3 = __builtin_nontemporal_load(src + 2 * t + 1537);
    __builtin_nontemporal_store(pack8v(a0, b0), dst + t);
    __builtin_nontemporal_store(pack8v(a1, b1), dst + t + 256);
    __builtin_nontemporal_store(pack8v(a2, b2), dst + t + 512);
    __builtin_nontemporal_store(pack8v(a3, b3), dst + t + 768);
  } else {                                 // ---- mask -> bias (1 block)
    const unsigned char* p8 = (const unsigned char*)msk;
    if (t == 0) {
      const float* pf = (const float*)msk;
      int allf = 1, anyone = 0;
      for (int i = 0; i < 64; ++i) {
        float f = pf[i];
        if (f != 0.0f && f != 1.0f) allf = 0;
        if (f == 1.0f) anyone = 1;
      }
      int any13 = 0;
      for (int i = 0; i < 256; ++i) if ((i & 3) && p8[i]) any13 = 1;
      fmt = (allf && anyone) ? 2 : (any13 ? 0 : 1);
    }
    __syncthreads();
    int j = t;
    if (j < 256) {
      int m;
      if (fmt == 2)      m = (((const float*)msk)[j] != 0.0f);
      else if (fmt == 0) m = (p8[j] != 0);
      else               m = (((const int*)msk)[j] != 0);
      bias[j] = m ? 0.0f : -1e30f;
    }
  }
}

// ======== weight transpose: W[K][N] f32 -> Wt[N][K] bf16, 64x128 tiles, nt ========
// tile[64][129] f32: pad 129 == 65 (mod 32) in row- and 8-row-terms -> bank behavior
// identical to the proven pad-65 pattern (store phase exact 2-way = free).
// Loads: wave covers 2 rows x 512B contiguous. Stores: 16B per thread.
__global__ __launch_bounds__(256) void transp_k(
    const float* __restrict__ Wq, const float* __restrict__ Wk,
    const float* __restrict__ Wv, const float* __restrict__ Wo,
    short* __restrict__ WqT, short* __restrict__ WkT,
    short* __restrict__ WvT, short* __restrict__ WoT)
{
  __shared__ float tile[64][129];
  int t = blockIdx.x;
  const float* W; short* Wt; int K, t0;
  if (t < 288)        { W = Wq; Wt = WqT; K = 1536; t0 = t; }
  else if (t < 1056)  { W = Wk; Wt = WkT; K = 4096; t0 = t - 288; }
  else if (t < 1824)  { W = Wv; Wt = WvT; K = 4096; t0 = t - 1056; }
  else                { W = Wo; Wt = WoT; K = 1536; t0 = t - 1824; }
  const int N = 1536;
  int ntx = K / 64;
  int k0 = (t0 % ntx) * 64, n0 = (t0 / ntx) * 128;
  #pragma unroll
  for (int i = 0; i < 8; ++i) {
    int fi = threadIdx.x + i * 256;        // float4 index in 64x32 grid
    int row = fi >> 5, c4 = fi & 31;
    f32x4 v = __builtin_nontemporal_load(
        (const f32x4*)(W + (size_t)(k0 + row) * N + n0 + c4 * 4));
    tile[row][c4 * 4 + 0] = v[0];
    tile[row][c4 * 4 + 1] = v[1];
    tile[row][c4 * 4 + 2] = v[2];
    tile[row][c4 * 4 + 3] = v[3];
  }
  __syncthreads();
  int n = threadIdx.x >> 3, kc = threadIdx.x & 7;   // n 0..31, kc 0..7
  #pragma unroll
  for (int half = 0; half < 4; ++half) {
    int nn = n + half * 32;
    s8bf o;
    #pragma unroll
    for (int j = 0; j < 8; ++j) o[j] = f2bf(tile[kc * 8 + j][nn]);
    __builtin_nontemporal_store(o, (s8bf*)(Wt + (size_t)(n0 + nn) * K + k0 + kc * 8));
  }
}

// ======== 4-phase GEMM, r7/r12-verified (0 conflicts): BM=256 BN=192 ========
// A[M][K] bf16 @ Bt[N][K]^T -> C[M][N].  MODE 0: bf16 store, 1: f32 store.
// LDS per buffer (56KB): A0@0(16K) A1@16K B0@32K(12K) B1@45056(12K); bufs 0/57344.
// Swizzle: phys slot = logical slot ^ (line&7), logical slot = 4*(row&1)+col16.
// Ledger: wid<4 issues 8 stage-instrs/tile, wid>=4 issues 6; boundary vmcnt(8)/(6).
template<int MODE>
__global__ __launch_bounds__(512, 2) void gemm4ph_k(
    const short* __restrict__ A, const short* __restrict__ Bt, void* __restrict__ C,
    int M, int N, int K)
{
  extern __shared__ char ldsb[];
  const int tid = threadIdx.x, wid = tid >> 6, lane = tid & 63;
  const int nbx = N / 192;
  const int nwg = gridDim.x, bid = blockIdx.x;
  const int swz = (bid & 7) * (nwg >> 3) + (bid >> 3);   // nwg % 8 == 0
  const int m0 = (swz / nbx) * 256, n0 = (swz % nbx) * 192;
  const int wm = wid >> 2, wn = wid & 3;
  const int NT = K / 64;

  const int l = lane & 15, h = lane >> 4;
  const int rdslot = (((l & 1) * 4 + h) ^ (l >> 1)) * 16;
  int aoff[8], boff[3];
  #pragma unroll
  for (int mf = 0; mf < 8; ++mf)
    aoff[mf] = (wm * 64 + mf * 8 + (l >> 1)) * 128 + rdslot;
  #pragma unroll
  for (int nf = 0; nf < 3; ++nf)
    boff[nf] = 32768 + (wn * 24 + nf * 8 + (l >> 1)) * 128 + rdslot;

  const int ls = (tid & 7) ^ ((tid >> 3) & 7);
  const int srow2 = 2 * (tid >> 3) + (ls >> 2);
  const int scol = (ls & 3) * 8;
  const short* sA_lo = A  + (size_t)(m0 + srow2) * K + scol;
  const short* sA_hi = A  + (size_t)(m0 + 128 + srow2) * K + scol;
  const short* sB_lo = Bt + (size_t)(n0 + srow2) * K + scol;
  const short* sB_hi = Bt + (size_t)(n0 + 128 + srow2) * K + scol;
  const int d16 = tid * 16;

  f32x4 acc[8][3] = {};
  s8bf av[4], av2[4], bk[3];

  gl_lds16(sA_lo,      ldsb + 0     + d16);
  gl_lds16(sA_hi,      ldsb + 8192  + d16);
  gl_lds16(sB_lo,      ldsb + 32768 + d16);
  if (wid < 4) gl_lds16(sB_hi,      ldsb + 40960 + d16);
  gl_lds16(sA_lo + 32, ldsb + 16384 + d16);
  gl_lds16(sA_hi + 32, ldsb + 24576 + d16);
  gl_lds16(sB_lo + 32, ldsb + 45056 + d16);
  if (wid < 4) gl_lds16(sB_hi + 32, ldsb + 53248 + d16);
  gl_lds16(sA_lo + 64, ldsb + 57344 + 0     + d16);
  gl_lds16(sA_hi + 64, ldsb + 57344 + 8192  + d16);
  gl_lds16(sB_lo + 64, ldsb + 57344 + 32768 + d16);
  if (wid < 4) gl_lds16(sB_hi + 64, ldsb + 57344 + 40960 + d16);
  if (wid < 4) asm volatile("s_waitcnt vmcnt(8)" ::: "memory");
  else         asm volatile("s_waitcnt vmcnt(6)" ::: "memory");
  __builtin_amdgcn_s_barrier();

  for (int t = 0; t < NT; ++t) {
    const int bo = (t & 1) * 57344, bo2 = bo ^ 57344;
    const int kt1 = ((t + 1) < NT ? (t + 1) : (NT - 1)) * 64;
    const int kt2 = ((t + 2) < NT ? (t + 2) : (NT - 1)) * 64;
    // ---- phase 0
    #pragma unroll
    for (int i = 0; i < 4; ++i) av[i] = *(const s8bf*)(ldsb + bo + aoff[i]);
    #pragma unroll
    for (int nf = 0; nf < 3; ++nf) bk[nf] = *(const s8bf*)(ldsb + bo + boff[nf]);
    gl_lds16(sA_lo + kt1 + 32, ldsb + bo2 + 16384 + d16);
    gl_lds16(sA_hi + kt1 + 32, ldsb + bo2 + 24576 + d16);
    __builtin_amdgcn_s_barrier();
    asm volatile("s_waitcnt lgkmcnt(0)" ::: "memory");
    __builtin_amdgcn_s_setprio(1);
    #pragma unroll
    for (int i = 0; i < 4; ++i)
      #pragma unroll
      for (int nf = 0; nf < 3; ++nf)
        acc[i][nf] = mfma16(av[i], bk[nf], acc[i][nf]);
    __builtin_amdgcn_s_setprio(0);
    __builtin_amdgcn_s_barrier();
    // ---- phase 1
    #pragma unroll
    for (int i = 0; i < 4; ++i) av2[i] = *(const s8bf*)(ldsb + bo + aoff[4 + i]);
    gl_lds16(sB_lo + kt1 + 32, ldsb + bo2 + 45056 + d16);
    if (wid < 4) gl_lds16(sB_hi + kt1 + 32, ldsb + bo2 + 53248 + d16);
    __builtin_amdgcn_s_barrier();
    asm volatile("s_waitcnt lgkmcnt(0)" ::: "memory");
    __builtin_amdgcn_s_setprio(1);
    #pragma unroll
    for (int i = 0; i < 4; ++i)
      #pragma unroll
      for (int nf = 0; nf < 3; ++nf)
        acc[4 + i][nf] = mfma16(av2[i], bk[nf], acc[4 + i][nf]);
    __builtin_amdgcn_s_setprio(0);
    if (wid < 4) asm volatile("s_waitcnt vmcnt(8)" ::: "memory");
    else         asm volatile("s_waitcnt vmcnt(6)" ::: "memory");
    __builtin_amdgcn_s_barrier();
    // ---- phase 2
    #pragma unroll
    for (int i = 0; i < 4; ++i) av[i] = *(const s8bf*)(ldsb + bo + 16384 + aoff[i]);
    #pragma unroll
    for (int nf = 0; nf < 3; ++nf) bk[nf] = *(const s8bf*)(ldsb + bo + 12288 + boff[nf]);
    gl_lds16(sA_lo + kt2, ldsb + bo + 0    + d16);
    gl_lds16(sA_hi + kt2, ldsb + bo + 8192 + d16);
    __builtin_amdgcn_s_barrier();
    asm volatile("s_waitcnt lgkmcnt(0)" ::: "memory");
    __builtin_amdgcn_s_setprio(1);
    #pragma unroll
    for (int i = 0; i < 4; ++i)
      #pragma unroll
      for (int nf = 0; nf < 3; ++nf)
        acc[i][nf] = mfma16(av[i], bk[nf], acc[i][nf]);
    __builtin_amdgcn_s_setprio(0);
    __builtin_amdgcn_s_barrier();
    // ---- phase 3
    #pragma unroll
    for (int i = 0; i < 4; ++i) av2[i] = *(const s8bf*)(ldsb + bo + 16384 + aoff[4 + i]);
    gl_lds16(sB_lo + kt2, ldsb + bo + 32768 + d16);
    if (wid < 4) gl_lds16(sB_hi + kt2, ldsb + bo + 40960 + d16);
    __builtin_amdgcn_s_barrier();
    asm volatile("s_waitcnt lgkmcnt(0)" ::: "memory");
    __builtin_amdgcn_s_setprio(1);
    #pragma unroll
    for (int i = 0; i < 4; ++i)
      #pragma unroll
      for (int nf = 0; nf < 3; ++nf)
        acc[4 + i][nf] = mfma16(av2[i], bk[nf], acc[4 + i][nf]);
    __builtin_amdgcn_s_setprio(0);
    if (wid < 4) asm volatile("s_waitcnt vmcnt(8)" ::: "memory");
    else         asm volatile("s_waitcnt vmcnt(6)" ::: "memory");
    __builtin_amdgcn_s_barrier();
  }
  asm volatile("s_waitcnt vmcnt(0)" ::: "memory");

  const int r0 = m0 + wm * 128 + ((lane >> 4) << 2);
  const int c0 = n0 + wn * 48 + (lane & 15);
  #pragma unroll
  for (int mf = 0; mf < 8; ++mf)
    #pragma unroll
    for (int nf = 0; nf < 3; ++nf)
      #pragma unroll
      for (int v = 0; v < 4; ++v) {
        int row = r0 + mf * 16 + v, col = c0 + nf * 16;
        float val = acc[mf][nf][v];
        if (MODE == 0) ((short*)C)[(size_t)row * N + col] = f2bf(val);
        else           ((float*)C)[(size_t)row * N + col] = val;
      }
}

// ---------------- m97-style GEMM for split-K K/V projection ----------------
// MODE 5: per-slice f32 partial store (no atomics): C[z][row][col], slice stride 256*3072
template<int MODE>
__global__ __launch_bounds__(256, 2) void gemm_bt_k(
    const short* __restrict__ A, const short* __restrict__ Bt, void* __restrict__ C,
    int M, int N, int K, int kchunk)
{
  __shared__ short aT[128 * 32];
  __shared__ short bT[128 * 32];
  const int m0 = blockIdx.x * 128, n0 = blockIdx.y * 128;
  const int wid = threadIdx.x >> 6, lane = threadIdx.x & 63;
  const int wr = wid >> 1, wc = wid & 1;
  const int k_lo = blockIdx.z * kchunk, k_hi = k_lo + kchunk;
  f32x4 acc[4][4] = {};
  const int srow = wid * 32 + (lane >> 2);
  const int skoff = (lane & 3) * 8;
  const short* aG = A + (size_t)(m0 + srow) * K + skoff;
  const short* bG = Bt + (size_t)(n0 + srow) * K + skoff;
  char* aL = (char*)aT + wid * 2048;
  char* bL = (char*)bT + wid * 2048;
  const short* ap = aT + (wr * 64 + (lane & 15)) * 32 + (lane >> 4) * 8;
  const short* bp = bT + (wc * 64 + (lane & 15)) * 32 + (lane >> 4) * 8;
  for (int k0 = k_lo; k0 < k_hi; k0 += 32) {
    gl_lds16(aG + k0, aL);
    gl_lds16(aG + (size_t)16 * K + k0, aL + 1024);
    gl_lds16(bG + k0, bL);
    gl_lds16(bG + (size_t)16 * K + k0, bL + 1024);
    __syncthreads();
    s8bf af[4], bf[4];
    #pragma unroll
    for (int i = 0; i < 4; ++i) {
      af[i] = *(const s8bf*)(ap + i * 512);
      bf[i] = *(const s8bf*)(bp + i * 512);
    }
    #pragma unroll
    for (int mi = 0; mi < 4; ++mi)
      #pragma unroll
      for (int ni = 0; ni < 4; ++ni)
        acc[mi][ni] = mfma16(af[mi], bf[ni], acc[mi][ni]);
    __syncthreads();
  }
  const int r0 = m0 + wr * 64 + ((lane >> 4) << 2);
  const int c0 = n0 + wc * 64 + (lane & 15);
  float* Cf = (float*)C + (size_t)blockIdx.z * 786432;
  #pragma unroll
  for (int mi = 0; mi < 4; ++mi)
    #pragma unroll
    for (int ni = 0; ni < 4; ++ni)
      #pragma unroll
      for (int v = 0; v < 4; ++v) {
        int row = r0 + mi * 16 + v, col = c0 + ni * 16;
        Cf[(size_t)row * N + col] = acc[mi][ni][v];
      }
}

// ---------------- reduce 8 split-K slices -> bf16 K (row-major) + V^T ----------------
__global__ void kv_reduce_k(const float* __restrict__ part, short* __restrict__ kbf,
                            short* __restrict__ vtbf) {
  int t = blockIdx.x * 256 + threadIdx.x;          // t < 196608
  int row = t / 768, c4 = (t % 768) * 4;
  float4 s = {0.f, 0.f, 0.f, 0.f};
  const float* p = part + (size_t)row * 3072 + c4;
  #pragma unroll
  for (int z = 0; z < 8; ++z) {
    float4 v = *(const float4*)(p + (size_t)z * 786432);
    s.x += v.x; s.y += v.y; s.z += v.z; s.w += v.w;
  }
  if (c4 < 1536) {
    short4 o = { f2bf(s.x), f2bf(s.y), f2bf(s.z), f2bf(s.w) };
    *(short4*)(kbf + (size_t)row * 1536 + c4) = o;
  } else {
    int b = row >> 7, j = row & 127, c = c4 - 1536;
    vtbf[((size_t)(b * 1536 + c + 0)) * 128 + j] = f2bf(s.x);
    vtbf[((size_t)(b * 1536 + c + 1)) * 128 + j] = f2bf(s.y);
    vtbf[((size_t)(b * 1536 + c + 2)) * 128 + j] = f2bf(s.z);
    vtbf[((size_t)(b * 1536 + c + 3)) * 128 + j] = f2bf(s.w);
  }
}

// ---------------- fused attention for one (i-tile=128, head, batch) ----------------
// LDS 48KB: kT [0,16K), vT [16K,32K), P: waves 0/1 alias dead kT, waves 2/3 at [32K,48K)
__global__ __launch_bounds__(256, 3) void attn_k(
    const short* __restrict__ q, const short* __restrict__ kk,
    const short* __restrict__ vt, const float* __restrict__ bias,
    short* __restrict__ ao)
{
  __shared__ char sm_[49152];
  const int it = blockIdx.x, h = blockIdx.y, b = blockIdx.z;
  const int wid = threadIdx.x >> 6, lane = threadIdx.x & 63;
  const int i0 = it * 128;
  char* kT = sm_;
  char* vT = sm_ + 16384;
  char* pB = (wid < 2) ? (sm_ + wid * 8192) : (sm_ + 16384 + wid * 8192);

  #pragma unroll
  for (int c = 0; c < 4; ++c) {
    int seg = c * 256 + wid * 64 + lane;
    int j = seg >> 3, ds = seg & 7;
    int dsrc = ds ^ (j & 7);
    gl_lds16(kk + ((size_t)(b * 128 + j) * 1536 + h * 64 + dsrc * 8),
             kT + c * 4096 + wid * 1024);
  }
  #pragma unroll
  for (int c = 0; c < 4; ++c) {
    int seg = c * 256 + wid * 64 + lane;
    int d = seg >> 4, js = seg & 15;
    int jsrc = js ^ (d & 7);
    gl_lds16(vt + ((size_t)(b * 1536 + h * 64 + d) * 128 + jsrc * 8),
             vT + c * 4096 + wid * 1024);
  }

  float bcol[8];
  #pragma unroll
  for (int nj = 0; nj < 8; ++nj) bcol[nj] = bias[b * 128 + nj * 16 + (lane & 15)];

  s8bf qf[2][2];
  #pragma unroll
  for (int mi = 0; mi < 2; ++mi)
    #pragma unroll
    for (int ks = 0; ks < 2; ++ks) {
      size_t row = (size_t)(b * 4096 + i0 + wid * 32 + mi * 16 + (lane & 15));
      qf[mi][ks] = *(const s8bf*)(q + row * 1536 + h * 64 + ks * 32 + (lane >> 4) * 8);
    }
  __syncthreads();

  f32x4 s[2][8] = {};
  #pragma unroll
  for (int ks = 0; ks < 2; ++ks) {
    int kd = ks * 32 + (lane >> 4) * 8;
    #pragma unroll
    for (int nj = 0; nj < 8; ++nj) {
      int j = nj * 16 + (lane & 15);
      s8bf kb = *(const s8bf*)(kT + j * 128 + ((2 * kd) ^ ((j & 7) << 4)));
      s[0][nj] = mfma16(qf[0][ks], kb, s[0][nj]);
      s[1][nj] = mfma16(qf[1][ks], kb, s[1][nj]);
    }
  }
  __syncthreads();   // kT handoff: all waves done with K before P overlays it

  float sm[2][4];
  #pragma unroll
  for (int mi = 0; mi < 2; ++mi)
    #pragma unroll
    for (int v = 0; v < 4; ++v) {
      float mx = -1e30f;
      #pragma unroll
      for (int nj = 0; nj < 8; ++nj) {
        float sv = s[mi][nj][v] * 0.125f + bcol[nj];
        s[mi][nj][v] = sv;
        mx = fmaxf(mx, sv);
      }
      mx = fmaxf(mx, __shfl_xor(mx, 1));
      mx = fmaxf(mx, __shfl_xor(mx, 2));
      mx = fmaxf(mx, __shfl_xor(mx, 4));
      mx = fmaxf(mx, __shfl_xor(mx, 8));
      float ss = 0.f;
      #pragma unroll
      for (int nj = 0; nj < 8; ++nj) {
        float p = __expf(s[mi][nj][v] - mx);
        s[mi][nj][v] = p;
        ss += p;
      }
      ss += __shfl_xor(ss, 1);
      ss += __shfl_xor(ss, 2);
      ss += __shfl_xor(ss, 4);
      ss += __shfl_xor(ss, 8);
      sm[mi][v] = ss;
    }

  #pragma unroll
  for (int mi = 0; mi < 2; ++mi)
    #pragma unroll
    for (int v = 0; v < 4; ++v) {
      int r = mi * 16 + ((lane >> 4) << 2) + v;
      char* base = pB + r * 256;
      #pragma unroll
      for (int nj = 0; nj < 8; ++nj) {
        int j = nj * 16 + (lane & 15);
        *(short*)(base + ((2 * j) ^ ((r & 7) << 4))) = f2bf(s[mi][nj][v]);
      }
    }
  __syncthreads();

  f32x4 o_[2][4] = {};
  #pragma unroll
  for (int ks = 0; ks < 4; ++ks) {
    int j = ks * 32 + (lane >> 4) * 8;
    s8bf pa[2];
    #pragma unroll
    for (int mi = 0; mi < 2; ++mi) {
      int r = mi * 16 + (lane & 15);
      pa[mi] = *(const s8bf*)(pB + r * 256 + ((2 * j) ^ ((r & 7) << 4)));
    }
    #pragma unroll
    for (int dj = 0; dj < 4; ++dj) {
      int d = dj * 16 + (lane & 15);
      s8bf vb = *(const s8bf*)(vT + d * 256 + ((2 * j) ^ ((d & 7) << 4)));
      o_[0][dj] = mfma16(pa[0], vb, o_[0][dj]);
      o_[1][dj] = mfma16(pa[1], vb, o_[1][dj]);
    }
  }

  #pragma unroll
  for (int mi = 0; mi < 2; ++mi)
    #pragma unroll
    for (int v = 0; v < 4; ++v) {
      int r = mi * 16 + ((lane >> 4) << 2) + v;
      float is = 1.0f / sm[mi][v];
      size_t row = (size_t)(b * 4096 + i0 + wid * 32 + r);
      #pragma unroll
      for (int dj = 0; dj < 4; ++dj) {
        int d = dj * 16 + (lane & 15);
        ao[row * 1536 + h * 64 + d] = f2bf(o_[mi][dj][v] * is);
      }
    }
}

extern "C" void kernel_launch(void* const* d_in, const int* in_sizes, int n_in,
                              void* d_out, int out_size, void* d_ws, size_t ws_size,
                              hipStream_t stream) {
  const float* x   = (const float*)d_in[0];
  const float* ctx = (const float*)d_in[1];
  const void*  msk = d_in[2];
  const float* Wq  = (const float*)d_in[3];
  const float* Wk  = (const float*)d_in[4];
  const float* Wv  = (const float*)d_in[5];
  const float* Wo  = (const float*)d_in[6];
  float* out = (float*)d_out;

  const int B = 2, NI = 4096, NT = 128, C = 1536, CC = 4096, H = 24;
  const int Mq = B * NI;  // 8192
  const int Mk = B * NT;  // 256

  size_t off = 0;
  auto carve = [&](size_t bytes) -> void* {
    void* p = (char*)d_ws + off;
    off += (bytes + 255) & ~(size_t)255;
    return p;
  };
  short* xbf   = (short*)carve((size_t)Mq * C * 2);   // reused as attn-out after Q-proj
  short* ctxbf = (short*)carve((size_t)Mk * CC * 2);
  short* WqT   = (short*)carve((size_t)C * C * 2);
  short* WkT   = (short*)carve((size_t)CC * C * 2);   // WvT must follow contiguously
  short* WvT   = (short*)carve((size_t)CC * C * 2);
  short* WoT   = (short*)carve((size_t)C * C * 2);
  short* qbf   = (short*)carve((size_t)Mq * C * 2);
  short* kbf   = (short*)carve((size_t)Mk * C * 2);
  short* vtbf  = (short*)carve((size_t)Mk * C * 2);
  float* bias  = (float*)carve(256 * 4);
  short* aout  = xbf;            // alias: x dead after Q-proj
  float* part  = out;            // d_out as split-K scratch (8*3MB=25.2MB <= 50.3MB,
                                 // fully overwritten by final O-proj -> deterministic)

  // allow 112KB dynamic LDS on the pipelined GEMMs (idempotent, capture-safe)
  hipFuncSetAttribute((const void*)gemm4ph_k<0>, hipFuncAttributeMaxDynamicSharedMemorySize, 114688);
  hipFuncSetAttribute((const void*)gemm4ph_k<1>, hipFuncAttributeMaxDynamicSharedMemorySize, 114688);

  // pre-pass: nontemporal casts + mask, then 64x128 nontemporal transposes
  cast_k<<<1665, 256, 0, stream>>>(x, ctx, msk, xbf, ctxbf, bias);
  transp_k<<<2112, 256, 0, stream>>>(Wq, Wk, Wv, Wo, WqT, WkT, WvT, WoT);

  // Q projection (4-phase GEMM, bf16 out): grid 32x8 = 256 (full CU coverage)
  gemm4ph_k<0><<<(Mq / 256) * (C / 192), 512, 114688, stream>>>(xbf, WqT, qbf, Mq, C, C);
  // K+V projections merged: split-K=8 f32 partials into d_out scratch (384 blocks), reduce
  gemm_bt_k<5><<<dim3(Mk / 128, 3072 / 128, 8), 256, 0, stream>>>(ctxbf, WkT, part, Mk, 3072, CC, 512);
  kv_reduce_k<<<768, 256, 0, stream>>>(part, kbf, vtbf);

  // fused attention
  attn_k<<<dim3(NI / 128, H, B), 256, 0, stream>>>(qbf, kbf, vtbf, bias, aout);

  // output projection (4-phase GEMM, f32 out)
  gemm4ph_k<1><<<(Mq / 256) * (C / 192), 512, 114688, stream>>>(aout, WoT, out, Mq, C, C);
}

// Round 17
// 180.560 us; speedup vs baseline: 1.0045x; 1.0045x over previous
//
#include <hip/hip_runtime.h>

typedef __attribute__((ext_vector_type(8))) short s8bf;     // 8 bf16 payload
typedef __attribute__((ext_vector_type(8))) __bf16 v8bf;    // MFMA operand type
typedef __attribute__((ext_vector_type(4))) float f32x4;

__device__ __forceinline__ short f2bf(float f) {
  union { float f; unsigned u; } v; v.f = f;
  unsigned r = v.u + 0x7FFFu + ((v.u >> 16) & 1u);  // RNE
  return (short)(r >> 16);
}

__device__ __forceinline__ s8bf pack8v(f32x4 a, f32x4 b) {
  s8bf o;
  o[0] = f2bf(a[0]); o[1] = f2bf(a[1]); o[2] = f2bf(a[2]); o[3] = f2bf(a[3]);
  o[4] = f2bf(b[0]); o[5] = f2bf(b[1]); o[6] = f2bf(b[2]); o[7] = f2bf(b[3]);
  return o;
}

__device__ __forceinline__ f32x4 mfma16(s8bf a, s8bf b, f32x4 c) {
  return __builtin_amdgcn_mfma_f32_16x16x32_bf16(
      __builtin_bit_cast(v8bf, a), __builtin_bit_cast(v8bf, b), c, 0, 0, 0);
}

__device__ __forceinline__ void gl_lds16(const void* g, void* l) {
  __builtin_amdgcn_global_load_lds(
      (const __attribute__((address_space(1))) unsigned*)g,
      (__attribute__((address_space(3))) unsigned*)l, 16, 0, 0);
}

// ======== cast kernel: f32 -> bf16, nontemporal streaming, 16B stores ========
__global__ __launch_bounds__(256) void cast_k(
    const float* __restrict__ x, const float* __restrict__ ctx,
    const void* __restrict__ msk,
    short* __restrict__ xbf, short* __restrict__ ctxbf, float* __restrict__ bias)
{
  __shared__ int fmt;
  const int blk = blockIdx.x;
  const int t = threadIdx.x;
  if (blk < 1664) {
    const f32x4* src;
    s8bf* dst;
    if (blk < 1536) { src = (const f32x4*)x + (size_t)blk * 2048;
                      dst = (s8bf*)xbf + (size_t)blk * 1024; }
    else            { src = (const f32x4*)ctx + (size_t)(blk - 1536) * 2048;
                      dst = (s8bf*)ctxbf + (size_t)(blk - 1536) * 1024; }
    f32x4 a0 = __builtin_nontemporal_load(src + 2 * t);
    f32x4 b0 = __builtin_nontemporal_load(src + 2 * t + 1);
    f32x4 a1 = __builtin_nontemporal_load(src + 2 * t + 512);
    f32x4 b1 = __builtin_nontemporal_load(src + 2 * t + 513);
    f32x4 a2 = __builtin_nontemporal_load(src + 2 * t + 1024);
    f32x4 b2 = __builtin_nontemporal_load(src + 2 * t + 1025);
    f32x4 a3 = __builtin_nontemporal_load(src + 2 * t + 1536);
    f32x4 b3 = __builtin_nontemporal_load(src + 2 * t + 1537);
    __builtin_nontemporal_store(pack8v(a0, b0), dst + t);
    __builtin_nontemporal_store(pack8v(a1, b1), dst + t + 256);
    __builtin_nontemporal_store(pack8v(a2, b2), dst + t + 512);
    __builtin_nontemporal_store(pack8v(a3, b3), dst + t + 768);
  } else {                                 // ---- mask -> bias (1 block)
    const unsigned char* p8 = (const unsigned char*)msk;
    if (t == 0) {
      const float* pf = (const float*)msk;
      int allf = 1, anyone = 0;
      for (int i = 0; i < 64; ++i) {
        float f = pf[i];
        if (f != 0.0f && f != 1.0f) allf = 0;
        if (f == 1.0f) anyone = 1;
      }
      int any13 = 0;
      for (int i = 0; i < 256; ++i) if ((i & 3) && p8[i]) any13 = 1;
      fmt = (allf && anyone) ? 2 : (any13 ? 0 : 1);
    }
    __syncthreads();
    int j = t;
    if (j < 256) {
      int m;
      if (fmt == 2)      m = (((const float*)msk)[j] != 0.0f);
      else if (fmt == 0) m = (p8[j] != 0);
      else               m = (((const int*)msk)[j] != 0);
      bias[j] = m ? 0.0f : -1e30f;
    }
  }
}

// ======== weight transpose: W[K][N] f32 -> Wt[N][K] bf16, 64x128 tiles, nt ========
// tile[64][129] f32: pad 129 == 65 (mod 32) in row- and 8-row-terms -> bank behavior
// identical to the proven pad-65 pattern (store phase exact 2-way = free).
// Loads: wave covers 2 rows x 512B contiguous. Stores: 16B per thread.
__global__ __launch_bounds__(256) void transp_k(
    const float* __restrict__ Wq, const float* __restrict__ Wk,
    const float* __restrict__ Wv, const float* __restrict__ Wo,
    short* __restrict__ WqT, short* __restrict__ WkT,
    short* __restrict__ WvT, short* __restrict__ WoT)
{
  __shared__ float tile[64][129];
  int t = blockIdx.x;
  const float* W; short* Wt; int K, t0;
  if (t < 288)        { W = Wq; Wt = WqT; K = 1536; t0 = t; }
  else if (t < 1056)  { W = Wk; Wt = WkT; K = 4096; t0 = t - 288; }
  else if (t < 1824)  { W = Wv; Wt = WvT; K = 4096; t0 = t - 1056; }
  else                { W = Wo; Wt = WoT; K = 1536; t0 = t - 1824; }
  const int N = 1536;
  int ntx = K / 64;
  int k0 = (t0 % ntx) * 64, n0 = (t0 / ntx) * 128;
  #pragma unroll
  for (int i = 0; i < 8; ++i) {
    int fi = threadIdx.x + i * 256;        // float4 index in 64x32 grid
    int row = fi >> 5, c4 = fi & 31;
    f32x4 v = __builtin_nontemporal_load(
        (const f32x4*)(W + (size_t)(k0 + row) * N + n0 + c4 * 4));
    tile[row][c4 * 4 + 0] = v[0];
    tile[row][c4 * 4 + 1] = v[1];
    tile[row][c4 * 4 + 2] = v[2];
    tile[row][c4 * 4 + 3] = v[3];
  }
  __syncthreads();
  int n = threadIdx.x >> 3, kc = threadIdx.x & 7;   // n 0..31, kc 0..7
  #pragma unroll
  for (int half = 0; half < 4; ++half) {
    int nn = n + half * 32;
    s8bf o;
    #pragma unroll
    for (int j = 0; j < 8; ++j) o[j] = f2bf(tile[kc * 8 + j][nn]);
    __builtin_nontemporal_store(o, (s8bf*)(Wt + (size_t)(n0 + nn) * K + k0 + kc * 8));
  }
}

// ======== 4-phase GEMM, r7/r12-verified (0 conflicts): BM=256 BN=192 ========
// A[M][K] bf16 @ Bt[N][K]^T -> C[M][N].  MODE 0: bf16 store, 1: f32 store.
// LDS per buffer (56KB): A0@0(16K) A1@16K B0@32K(12K) B1@45056(12K); bufs 0/57344.
// Swizzle: phys slot = logical slot ^ (line&7), logical slot = 4*(row&1)+col16.
// Ledger: wid<4 issues 8 stage-instrs/tile, wid>=4 issues 6; boundary vmcnt(8)/(6).
template<int MODE>
__global__ __launch_bounds__(512, 2) void gemm4ph_k(
    const short* __restrict__ A, const short* __restrict__ Bt, void* __restrict__ C,
    int M, int N, int K)
{
  extern __shared__ char ldsb[];
  const int tid = threadIdx.x, wid = tid >> 6, lane = tid & 63;
  const int nbx = N / 192;
  const int nwg = gridDim.x, bid = blockIdx.x;
  const int swz = (bid & 7) * (nwg >> 3) + (bid >> 3);   // nwg % 8 == 0
  const int m0 = (swz / nbx) * 256, n0 = (swz % nbx) * 192;
  const int wm = wid >> 2, wn = wid & 3;
  const int NT = K / 64;

  const int l = lane & 15, h = lane >> 4;
  const int rdslot = (((l & 1) * 4 + h) ^ (l >> 1)) * 16;
  int aoff[8], boff[3];
  #pragma unroll
  for (int mf = 0; mf < 8; ++mf)
    aoff[mf] = (wm * 64 + mf * 8 + (l >> 1)) * 128 + rdslot;
  #pragma unroll
  for (int nf = 0; nf < 3; ++nf)
    boff[nf] = 32768 + (wn * 24 + nf * 8 + (l >> 1)) * 128 + rdslot;

  const int ls = (tid & 7) ^ ((tid >> 3) & 7);
  const int srow2 = 2 * (tid >> 3) + (ls >> 2);
  const int scol = (ls & 3) * 8;
  const short* sA_lo = A  + (size_t)(m0 + srow2) * K + scol;
  const short* sA_hi = A  + (size_t)(m0 + 128 + srow2) * K + scol;
  const short* sB_lo = Bt + (size_t)(n0 + srow2) * K + scol;
  const short* sB_hi = Bt + (size_t)(n0 + 128 + srow2) * K + scol;
  const int d16 = tid * 16;

  f32x4 acc[8][3] = {};
  s8bf av[4], av2[4], bk[3];

  gl_lds16(sA_lo,      ldsb + 0     + d16);
  gl_lds16(sA_hi,      ldsb + 8192  + d16);
  gl_lds16(sB_lo,      ldsb + 32768 + d16);
  if (wid < 4) gl_lds16(sB_hi,      ldsb + 40960 + d16);
  gl_lds16(sA_lo + 32, ldsb + 16384 + d16);
  gl_lds16(sA_hi + 32, ldsb + 24576 + d16);
  gl_lds16(sB_lo + 32, ldsb + 45056 + d16);
  if (wid < 4) gl_lds16(sB_hi + 32, ldsb + 53248 + d16);
  gl_lds16(sA_lo + 64, ldsb + 57344 + 0     + d16);
  gl_lds16(sA_hi + 64, ldsb + 57344 + 8192  + d16);
  gl_lds16(sB_lo + 64, ldsb + 57344 + 32768 + d16);
  if (wid < 4) gl_lds16(sB_hi + 64, ldsb + 57344 + 40960 + d16);
  if (wid < 4) asm volatile("s_waitcnt vmcnt(8)" ::: "memory");
  else         asm volatile("s_waitcnt vmcnt(6)" ::: "memory");
  __builtin_amdgcn_s_barrier();

  for (int t = 0; t < NT; ++t) {
    const int bo = (t & 1) * 57344, bo2 = bo ^ 57344;
    const int kt1 = ((t + 1) < NT ? (t + 1) : (NT - 1)) * 64;
    const int kt2 = ((t + 2) < NT ? (t + 2) : (NT - 1)) * 64;
    // ---- phase 0
    #pragma unroll
    for (int i = 0; i < 4; ++i) av[i] = *(const s8bf*)(ldsb + bo + aoff[i]);
    #pragma unroll
    for (int nf = 0; nf < 3; ++nf) bk[nf] = *(const s8bf*)(ldsb + bo + boff[nf]);
    gl_lds16(sA_lo + kt1 + 32, ldsb + bo2 + 16384 + d16);
    gl_lds16(sA_hi + kt1 + 32, ldsb + bo2 + 24576 + d16);
    __builtin_amdgcn_s_barrier();
    asm volatile("s_waitcnt lgkmcnt(0)" ::: "memory");
    __builtin_amdgcn_s_setprio(1);
    #pragma unroll
    for (int i = 0; i < 4; ++i)
      #pragma unroll
      for (int nf = 0; nf < 3; ++nf)
        acc[i][nf] = mfma16(av[i], bk[nf], acc[i][nf]);
    __builtin_amdgcn_s_setprio(0);
    __builtin_amdgcn_s_barrier();
    // ---- phase 1
    #pragma unroll
    for (int i = 0; i < 4; ++i) av2[i] = *(const s8bf*)(ldsb + bo + aoff[4 + i]);
    gl_lds16(sB_lo + kt1 + 32, ldsb + bo2 + 45056 + d16);
    if (wid < 4) gl_lds16(sB_hi + kt1 + 32, ldsb + bo2 + 53248 + d16);
    __builtin_amdgcn_s_barrier();
    asm volatile("s_waitcnt lgkmcnt(0)" ::: "memory");
    __builtin_amdgcn_s_setprio(1);
    #pragma unroll
    for (int i = 0; i < 4; ++i)
      #pragma unroll
      for (int nf = 0; nf < 3; ++nf)
        acc[4 + i][nf] = mfma16(av2[i], bk[nf], acc[4 + i][nf]);
    __builtin_amdgcn_s_setprio(0);
    if (wid < 4) asm volatile("s_waitcnt vmcnt(8)" ::: "memory");
    else         asm volatile("s_waitcnt vmcnt(6)" ::: "memory");
    __builtin_amdgcn_s_barrier();
    // ---- phase 2
    #pragma unroll
    for (int i = 0; i < 4; ++i) av[i] = *(const s8bf*)(ldsb + bo + 16384 + aoff[i]);
    #pragma unroll
    for (int nf = 0; nf < 3; ++nf) bk[nf] = *(const s8bf*)(ldsb + bo + 12288 + boff[nf]);
    gl_lds16(sA_lo + kt2, ldsb + bo + 0    + d16);
    gl_lds16(sA_hi + kt2, ldsb + bo + 8192 + d16);
    __builtin_amdgcn_s_barrier();
    asm volatile("s_waitcnt lgkmcnt(0)" ::: "memory");
    __builtin_amdgcn_s_setprio(1);
    #pragma unroll
    for (int i = 0; i < 4; ++i)
      #pragma unroll
      for (int nf = 0; nf < 3; ++nf)
        acc[i][nf] = mfma16(av[i], bk[nf], acc[i][nf]);
    __builtin_amdgcn_s_setprio(0);
    __builtin_amdgcn_s_barrier();
    // ---- phase 3
    #pragma unroll
    for (int i = 0; i < 4; ++i) av2[i] = *(const s8bf*)(ldsb + bo + 16384 + aoff[4 + i]);
    gl_lds16(sB_lo + kt2, ldsb + bo + 32768 + d16);
    if (wid < 4) gl_lds16(sB_hi + kt2, ldsb + bo + 40960 + d16);
    __builtin_amdgcn_s_barrier();
    asm volatile("s_waitcnt lgkmcnt(0)" ::: "memory");
    __builtin_amdgcn_s_setprio(1);
    #pragma unroll
    for (int i = 0; i < 4; ++i)
      #pragma unroll
      for (int nf = 0; nf < 3; ++nf)
        acc[4 + i][nf] = mfma16(av2[i], bk[nf], acc[4 + i][nf]);
    __builtin_amdgcn_s_setprio(0);
    if (wid < 4) asm volatile("s_waitcnt vmcnt(8)" ::: "memory");
    else         asm volatile("s_waitcnt vmcnt(6)" ::: "memory");
    __builtin_amdgcn_s_barrier();
  }
  asm volatile("s_waitcnt vmcnt(0)" ::: "memory");

  const int r0 = m0 + wm * 128 + ((lane >> 4) << 2);
  const int c0 = n0 + wn * 48 + (lane & 15);
  #pragma unroll
  for (int mf = 0; mf < 8; ++mf)
    #pragma unroll
    for (int nf = 0; nf < 3; ++nf)
      #pragma unroll
      for (int v = 0; v < 4; ++v) {
        int row = r0 + mf * 16 + v, col = c0 + nf * 16;
        float val = acc[mf][nf][v];
        if (MODE == 0) ((short*)C)[(size_t)row * N + col] = f2bf(val);
        else           ((float*)C)[(size_t)row * N + col] = val;
      }
}

// ---------------- m97-style GEMM for split-K K/V projection ----------------
// MODE 5: per-slice f32 partial store (no atomics): C[z][row][col], slice stride 256*3072
template<int MODE>
__global__ __launch_bounds__(256, 2) void gemm_bt_k(
    const short* __restrict__ A, const short* __restrict__ Bt, void* __restrict__ C,
    int M, int N, int K, int kchunk)
{
  __shared__ short aT[128 * 32];
  __shared__ short bT[128 * 32];
  const int m0 = blockIdx.x * 128, n0 = blockIdx.y * 128;
  const int wid = threadIdx.x >> 6, lane = threadIdx.x & 63;
  const int wr = wid >> 1, wc = wid & 1;
  const int k_lo = blockIdx.z * kchunk, k_hi = k_lo + kchunk;
  f32x4 acc[4][4] = {};
  const int srow = wid * 32 + (lane >> 2);
  const int skoff = (lane & 3) * 8;
  const short* aG = A + (size_t)(m0 + srow) * K + skoff;
  const short* bG = Bt + (size_t)(n0 + srow) * K + skoff;
  char* aL = (char*)aT + wid * 2048;
  char* bL = (char*)bT + wid * 2048;
  const short* ap = aT + (wr * 64 + (lane & 15)) * 32 + (lane >> 4) * 8;
  const short* bp = bT + (wc * 64 + (lane & 15)) * 32 + (lane >> 4) * 8;
  for (int k0 = k_lo; k0 < k_hi; k0 += 32) {
    gl_lds16(aG + k0, aL);
    gl_lds16(aG + (size_t)16 * K + k0, aL + 1024);
    gl_lds16(bG + k0, bL);
    gl_lds16(bG + (size_t)16 * K + k0, bL + 1024);
    __syncthreads();
    s8bf af[4], bf[4];
    #pragma unroll
    for (int i = 0; i < 4; ++i) {
      af[i] = *(const s8bf*)(ap + i * 512);
      bf[i] = *(const s8bf*)(bp + i * 512);
    }
    #pragma unroll
    for (int mi = 0; mi < 4; ++mi)
      #pragma unroll
      for (int ni = 0; ni < 4; ++ni)
        acc[mi][ni] = mfma16(af[mi], bf[ni], acc[mi][ni]);
    __syncthreads();
  }
  const int r0 = m0 + wr * 64 + ((lane >> 4) << 2);
  const int c0 = n0 + wc * 64 + (lane & 15);
  float* Cf = (float*)C + (size_t)blockIdx.z * 786432;
  #pragma unroll
  for (int mi = 0; mi < 4; ++mi)
    #pragma unroll
    for (int ni = 0; ni < 4; ++ni)
      #pragma unroll
      for (int v = 0; v < 4; ++v) {
        int row = r0 + mi * 16 + v, col = c0 + ni * 16;
        Cf[(size_t)row * N + col] = acc[mi][ni][v];
      }
}

// ---------------- reduce 8 split-K slices -> bf16 K (row-major) + V^T ----------------
__global__ void kv_reduce_k(const float* __restrict__ part, short* __restrict__ kbf,
                            short* __restrict__ vtbf) {
  int t = blockIdx.x * 256 + threadIdx.x;          // t < 196608
  int row = t / 768, c4 = (t % 768) * 4;
  float4 s = {0.f, 0.f, 0.f, 0.f};
  const float* p = part + (size_t)row * 3072 + c4;
  #pragma unroll
  for (int z = 0; z < 8; ++z) {
    float4 v = *(const float4*)(p + (size_t)z * 786432);
    s.x += v.x; s.y += v.y; s.z += v.z; s.w += v.w;
  }
  if (c4 < 1536) {
    short4 o = { f2bf(s.x), f2bf(s.y), f2bf(s.z), f2bf(s.w) };
    *(short4*)(kbf + (size_t)row * 1536 + c4) = o;
  } else {
    int b = row >> 7, j = row & 127, c = c4 - 1536;
    vtbf[((size_t)(b * 1536 + c + 0)) * 128 + j] = f2bf(s.x);
    vtbf[((size_t)(b * 1536 + c + 1)) * 128 + j] = f2bf(s.y);
    vtbf[((size_t)(b * 1536 + c + 2)) * 128 + j] = f2bf(s.z);
    vtbf[((size_t)(b * 1536 + c + 3)) * 128 + j] = f2bf(s.w);
  }
}

// ---------------- fused attention for one (i-tile=128, head, batch) ----------------
// LDS 48KB: kT [0,16K), vT [16K,32K), P: waves 0/1 alias dead kT, waves 2/3 at [32K,48K)
__global__ __launch_bounds__(256, 3) void attn_k(
    const short* __restrict__ q, const short* __restrict__ kk,
    const short* __restrict__ vt, const float* __restrict__ bias,
    short* __restrict__ ao)
{
  __shared__ char sm_[49152];
  const int it = blockIdx.x, h = blockIdx.y, b = blockIdx.z;
  const int wid = threadIdx.x >> 6, lane = threadIdx.x & 63;
  const int i0 = it * 128;
  char* kT = sm_;
  char* vT = sm_ + 16384;
  char* pB = (wid < 2) ? (sm_ + wid * 8192) : (sm_ + 16384 + wid * 8192);

  #pragma unroll
  for (int c = 0; c < 4; ++c) {
    int seg = c * 256 + wid * 64 + lane;
    int j = seg >> 3, ds = seg & 7;
    int dsrc = ds ^ (j & 7);
    gl_lds16(kk + ((size_t)(b * 128 + j) * 1536 + h * 64 + dsrc * 8),
             kT + c * 4096 + wid * 1024);
  }
  #pragma unroll
  for (int c = 0; c < 4; ++c) {
    int seg = c * 256 + wid * 64 + lane;
    int d = seg >> 4, js = seg & 15;
    int jsrc = js ^ (d & 7);
    gl_lds16(vt + ((size_t)(b * 1536 + h * 64 + d) * 128 + jsrc * 8),
             vT + c * 4096 + wid * 1024);
  }

  float bcol[8];
  #pragma unroll
  for (int nj = 0; nj < 8; ++nj) bcol[nj] = bias[b * 128 + nj * 16 + (lane & 15)];

  s8bf qf[2][2];
  #pragma unroll
  for (int mi = 0; mi < 2; ++mi)
    #pragma unroll
    for (int ks = 0; ks < 2; ++ks) {
      size_t row = (size_t)(b * 4096 + i0 + wid * 32 + mi * 16 + (lane & 15));
      qf[mi][ks] = *(const s8bf*)(q + row * 1536 + h * 64 + ks * 32 + (lane >> 4) * 8);
    }
  __syncthreads();

  f32x4 s[2][8] = {};
  #pragma unroll
  for (int ks = 0; ks < 2; ++ks) {
    int kd = ks * 32 + (lane >> 4) * 8;
    #pragma unroll
    for (int nj = 0; nj < 8; ++nj) {
      int j = nj * 16 + (lane & 15);
      s8bf kb = *(const s8bf*)(kT + j * 128 + ((2 * kd) ^ ((j & 7) << 4)));
      s[0][nj] = mfma16(qf[0][ks], kb, s[0][nj]);
      s[1][nj] = mfma16(qf[1][ks], kb, s[1][nj]);
    }
  }
  __syncthreads();   // kT handoff: all waves done with K before P overlays it

  float sm[2][4];
  #pragma unroll
  for (int mi = 0; mi < 2; ++mi)
    #pragma unroll
    for (int v = 0; v < 4; ++v) {
      float mx = -1e30f;
      #pragma unroll
      for (int nj = 0; nj < 8; ++nj) {
        float sv = s[mi][nj][v] * 0.125f + bcol[nj];
        s[mi][nj][v] = sv;
        mx = fmaxf(mx, sv);
      }
      mx = fmaxf(mx, __shfl_xor(mx, 1));
      mx = fmaxf(mx, __shfl_xor(mx, 2));
      mx = fmaxf(mx, __shfl_xor(mx, 4));
      mx = fmaxf(mx, __shfl_xor(mx, 8));
      float ss = 0.f;
      #pragma unroll
      for (int nj = 0; nj < 8; ++nj) {
        float p = __expf(s[mi][nj][v] - mx);
        s[mi][nj][v] = p;
        ss += p;
      }
      ss += __shfl_xor(ss, 1);
      ss += __shfl_xor(ss, 2);
      ss += __shfl_xor(ss, 4);
      ss += __shfl_xor(ss, 8);
      sm[mi][v] = ss;
    }

  #pragma unroll
  for (int mi = 0; mi < 2; ++mi)
    #pragma unroll
    for (int v = 0; v < 4; ++v) {
      int r = mi * 16 + ((lane >> 4) << 2) + v;
      char* base = pB + r * 256;
      #pragma unroll
      for (int nj = 0; nj < 8; ++nj) {
        int j = nj * 16 + (lane & 15);
        *(short*)(base + ((2 * j) ^ ((r & 7) << 4))) = f2bf(s[mi][nj][v]);
      }
    }
  __syncthreads();

  f32x4 o_[2][4] = {};
  #pragma unroll
  for (int ks = 0; ks < 4; ++ks) {
    int j = ks * 32 + (lane >> 4) * 8;
    s8bf pa[2];
    #pragma unroll
    for (int mi = 0; mi < 2; ++mi) {
      int r = mi * 16 + (lane & 15);
      pa[mi] = *(const s8bf*)(pB + r * 256 + ((2 * j) ^ ((r & 7) << 4)));
    }
    #pragma unroll
    for (int dj = 0; dj < 4; ++dj) {
      int d = dj * 16 + (lane & 15);
      s8bf vb = *(const s8bf*)(vT + d * 256 + ((2 * j) ^ ((d & 7) << 4)));
      o_[0][dj] = mfma16(pa[0], vb, o_[0][dj]);
      o_[1][dj] = mfma16(pa[1], vb, o_[1][dj]);
    }
  }

  #pragma unroll
  for (int mi = 0; mi < 2; ++mi)
    #pragma unroll
    for (int v = 0; v < 4; ++v) {
      int r = mi * 16 + ((lane >> 4) << 2) + v;
      float is = 1.0f / sm[mi][v];
      size_t row = (size_t)(b * 4096 + i0 + wid * 32 + r);
      #pragma unroll
      for (int dj = 0; dj < 4; ++dj) {
        int d = dj * 16 + (lane & 15);
        ao[row * 1536 + h * 64 + d] = f2bf(o_[mi][dj][v] * is);
      }
    }
}

extern "C" void kernel_launch(void* const* d_in, const int* in_sizes, int n_in,
                              void* d_out, int out_size, void* d_ws, size_t ws_size,
                              hipStream_t stream) {
  const float* x   = (const float*)d_in[0];
  const float* ctx = (const float*)d_in[1];
  const void*  msk = d_in[2];
  const float* Wq  = (const float*)d_in[3];
  const float* Wk  = (const float*)d_in[4];
  const float* Wv  = (const float*)d_in[5];
  const float* Wo  = (const float*)d_in[6];
  float* out = (float*)d_out;

  const int B = 2, NI = 4096, NT = 128, C = 1536, CC = 4096, H = 24;
  const int Mq = B * NI;  // 8192
  const int Mk = B * NT;  // 256

  size_t off = 0;
  auto carve = [&](size_t bytes) -> void* {
    void* p = (char*)d_ws + off;
    off += (bytes + 255) & ~(size_t)255;
    return p;
  };
  short* xbf   = (short*)carve((size_t)Mq * C * 2);   // reused as attn-out after Q-proj
  short* ctxbf = (short*)carve((size_t)Mk * CC * 2);
  short* WqT   = (short*)carve((size_t)C * C * 2);
  short* WkT   = (short*)carve((size_t)CC * C * 2);   // WvT must follow contiguously
  short* WvT   = (short*)carve((size_t)CC * C * 2);
  short* WoT   = (short*)carve((size_t)C * C * 2);
  short* qbf   = (short*)carve((size_t)Mq * C * 2);
  short* kbf   = (short*)carve((size_t)Mk * C * 2);
  short* vtbf  = (short*)carve((size_t)Mk * C * 2);
  float* bias  = (float*)carve(256 * 4);
  short* aout  = xbf;            // alias: x dead after Q-proj
  float* part  = out;            // d_out as split-K scratch (8*3MB=25.2MB <= 50.3MB,
                                 // fully overwritten by final O-proj -> deterministic)

  // allow 112KB dynamic LDS on the pipelined GEMMs (idempotent, capture-safe)
  hipFuncSetAttribute((const void*)gemm4ph_k<0>, hipFuncAttributeMaxDynamicSharedMemorySize, 114688);
  hipFuncSetAttribute((const void*)gemm4ph_k<1>, hipFuncAttributeMaxDynamicSharedMemorySize, 114688);

  // pre-pass: nontemporal casts + mask, then 64x128 nontemporal transposes
  cast_k<<<1665, 256, 0, stream>>>(x, ctx, msk, xbf, ctxbf, bias);
  transp_k<<<2112, 256, 0, stream>>>(Wq, Wk, Wv, Wo, WqT, WkT, WvT, WoT);

  // Q projection (4-phase GEMM, bf16 out): grid 32x8 = 256 (full CU coverage)
  gemm4ph_k<0><<<(Mq / 256) * (C / 192), 512, 114688, stream>>>(xbf, WqT, qbf, Mq, C, C);
  // K+V projections merged: split-K=8 f32 partials into d_out scratch (384 blocks), reduce
  gemm_bt_k<5><<<dim3(Mk / 128, 3072 / 128, 8), 256, 0, stream>>>(ctxbf, WkT, part, Mk, 3072, CC, 512);
  kv_reduce_k<<<768, 256, 0, stream>>>(part, kbf, vtbf);

  // fused attention
  attn_k<<<dim3(NI / 128, H, B), 256, 0, stream>>>(qbf, kbf, vtbf, bias, aout);

  // output projection (4-phase GEMM, f32 out)
  gemm4ph_k<1><<<(Mq / 256) * (C / 192), 512, 114688, stream>>>(aout, WoT, out, Mq, C, C);
}

// Round 18
// 168.235 us; speedup vs baseline: 1.0781x; 1.0733x over previous
//
#include <hip/hip_runtime.h>

typedef __attribute__((ext_vector_type(8))) short s8bf;     // 8 bf16 payload
typedef __attribute__((ext_vector_type(8))) __bf16 v8bf;    // MFMA operand type
typedef __attribute__((ext_vector_type(4))) float f32x4;

__device__ __forceinline__ short f2bf(float f) {
  union { float f; unsigned u; } v; v.f = f;
  unsigned r = v.u + 0x7FFFu + ((v.u >> 16) & 1u);  // RNE
  return (short)(r >> 16);
}

__device__ __forceinline__ s8bf pack8(float4 a, float4 b) {
  s8bf o;
  o[0] = f2bf(a.x); o[1] = f2bf(a.y); o[2] = f2bf(a.z); o[3] = f2bf(a.w);
  o[4] = f2bf(b.x); o[5] = f2bf(b.y); o[6] = f2bf(b.z); o[7] = f2bf(b.w);
  return o;
}

__device__ __forceinline__ f32x4 mfma16(s8bf a, s8bf b, f32x4 c) {
  return __builtin_amdgcn_mfma_f32_16x16x32_bf16(
      __builtin_bit_cast(v8bf, a), __builtin_bit_cast(v8bf, b), c, 0, 0, 0);
}

__device__ __forceinline__ void gl_lds16(const void* g, void* l) {
  __builtin_amdgcn_global_load_lds(
      (const __attribute__((address_space(1))) unsigned*)g,
      (__attribute__((address_space(3))) unsigned*)l, 16, 0, 0);
}

// ======== cast kernel: f32 -> bf16 with 16B stores (cached: GEMMs re-read output) ========
__global__ __launch_bounds__(256) void cast_k(
    const float* __restrict__ x, const float* __restrict__ ctx,
    const void* __restrict__ msk,
    short* __restrict__ xbf, short* __restrict__ ctxbf, float* __restrict__ bias)
{
  __shared__ int fmt;
  const int blk = blockIdx.x;
  const int t = threadIdx.x;
  if (blk < 1664) {
    const float4* src;
    s8bf* dst;
    if (blk < 1536) { src = (const float4*)x + (size_t)blk * 2048;
                      dst = (s8bf*)xbf + (size_t)blk * 1024; }
    else            { src = (const float4*)ctx + (size_t)(blk - 1536) * 2048;
                      dst = (s8bf*)ctxbf + (size_t)(blk - 1536) * 1024; }
    float4 a0 = src[2 * t];        float4 b0 = src[2 * t + 1];
    float4 a1 = src[2 * t + 512];  float4 b1 = src[2 * t + 513];
    float4 a2 = src[2 * t + 1024]; float4 b2 = src[2 * t + 1025];
    float4 a3 = src[2 * t + 1536]; float4 b3 = src[2 * t + 1537];
    dst[t]       = pack8(a0, b0);
    dst[t + 256] = pack8(a1, b1);
    dst[t + 512] = pack8(a2, b2);
    dst[t + 768] = pack8(a3, b3);
  } else {                                 // ---- mask -> bias (1 block)
    const unsigned char* p8 = (const unsigned char*)msk;
    if (t == 0) {
      const float* pf = (const float*)msk;
      int allf = 1, anyone = 0;
      for (int i = 0; i < 64; ++i) {
        float f = pf[i];
        if (f != 0.0f && f != 1.0f) allf = 0;
        if (f == 1.0f) anyone = 1;
      }
      int any13 = 0;
      for (int i = 0; i < 256; ++i) if ((i & 3) && p8[i]) any13 = 1;
      fmt = (allf && anyone) ? 2 : (any13 ? 0 : 1);
    }
    __syncthreads();
    int j = t;
    if (j < 256) {
      int m;
      if (fmt == 2)      m = (((const float*)msk)[j] != 0.0f);
      else if (fmt == 0) m = (p8[j] != 0);
      else               m = (((const int*)msk)[j] != 0);
      bias[j] = m ? 0.0f : -1e30f;
    }
  }
}

// ======== weight transpose kernel: W[K][N] f32 -> Wt[N][K] bf16, 64x64 tiles ========
__global__ __launch_bounds__(256) void transp_k(
    const float* __restrict__ Wq, const float* __restrict__ Wk,
    const float* __restrict__ Wv, const float* __restrict__ Wo,
    short* __restrict__ WqT, short* __restrict__ WkT,
    short* __restrict__ WvT, short* __restrict__ WoT)
{
  __shared__ float tile[64][65];
  int t = blockIdx.x;
  const float* W; short* Wt; int K, t0;
  if (t < 576)       { W = Wq; Wt = WqT; K = 1536; t0 = t; }
  else if (t < 2112) { W = Wk; Wt = WkT; K = 4096; t0 = t - 576; }
  else if (t < 3648) { W = Wv; Wt = WvT; K = 4096; t0 = t - 2112; }
  else               { W = Wo; Wt = WoT; K = 1536; t0 = t - 3648; }
  const int N = 1536;
  int ntx = K / 64;
  int k0 = (t0 % ntx) * 64, n0 = (t0 / ntx) * 64;
  int r = threadIdx.x >> 4;
  int c4 = threadIdx.x & 15;
  #pragma unroll
  for (int i = 0; i < 4; ++i) {
    float4 v = *(const float4*)(W + (size_t)(k0 + r + i * 16) * N + n0 + c4 * 4);
    tile[r + i * 16][c4 * 4 + 0] = v.x;
    tile[r + i * 16][c4 * 4 + 1] = v.y;
    tile[r + i * 16][c4 * 4 + 2] = v.z;
    tile[r + i * 16][c4 * 4 + 3] = v.w;
  }
  __syncthreads();
  int n = threadIdx.x >> 3, kc = threadIdx.x & 7;
  #pragma unroll
  for (int half = 0; half < 2; ++half) {
    int nn = n + half * 32;
    s8bf o;
    #pragma unroll
    for (int j = 0; j < 8; ++j) o[j] = f2bf(tile[kc * 8 + j][nn]);
    *(s8bf*)(Wt + (size_t)(n0 + nn) * K + k0 + kc * 8) = o;
  }
}

// ======== 4-phase GEMM, r7/r12/r14-verified (0 conflicts): BM=256 BN=192 ========
// A[M][K] bf16 @ Bt[N][K]^T -> C[M][N].  MODE 0: bf16 store, 1: f32 store.
// LDS per buffer (56KB): A0@0(16K) A1@16K B0@32K(12K) B1@45056(12K); bufs 0/57344.
// Swizzle: phys slot = logical slot ^ (line&7), logical slot = 4*(row&1)+col16.
// Ledger: wid<4 issues 8 stage-instrs/tile, wid>=4 issues 6; boundary vmcnt(8)/(6).
template<int MODE>
__global__ __launch_bounds__(512, 2) void gemm4ph_k(
    const short* __restrict__ A, const short* __restrict__ Bt, void* __restrict__ C,
    int M, int N, int K)
{
  extern __shared__ char ldsb[];
  const int tid = threadIdx.x, wid = tid >> 6, lane = tid & 63;
  const int nbx = N / 192;
  const int nwg = gridDim.x, bid = blockIdx.x;
  const int swz = (bid & 7) * (nwg >> 3) + (bid >> 3);   // nwg % 8 == 0
  const int m0 = (swz / nbx) * 256, n0 = (swz % nbx) * 192;
  const int wm = wid >> 2, wn = wid & 3;
  const int NT = K / 64;

  const int l = lane & 15, h = lane >> 4;
  const int rdslot = (((l & 1) * 4 + h) ^ (l >> 1)) * 16;
  int aoff[8], boff[3];
  #pragma unroll
  for (int mf = 0; mf < 8; ++mf)
    aoff[mf] = (wm * 64 + mf * 8 + (l >> 1)) * 128 + rdslot;
  #pragma unroll
  for (int nf = 0; nf < 3; ++nf)
    boff[nf] = 32768 + (wn * 24 + nf * 8 + (l >> 1)) * 128 + rdslot;

  const int ls = (tid & 7) ^ ((tid >> 3) & 7);
  const int srow2 = 2 * (tid >> 3) + (ls >> 2);
  const int scol = (ls & 3) * 8;
  const short* sA_lo = A  + (size_t)(m0 + srow2) * K + scol;
  const short* sA_hi = A  + (size_t)(m0 + 128 + srow2) * K + scol;
  const short* sB_lo = Bt + (size_t)(n0 + srow2) * K + scol;
  const short* sB_hi = Bt + (size_t)(n0 + 128 + srow2) * K + scol;
  const int d16 = tid * 16;

  f32x4 acc[8][3] = {};
  s8bf av[4], av2[4], bk[3];

  gl_lds16(sA_lo,      ldsb + 0     + d16);
  gl_lds16(sA_hi,      ldsb + 8192  + d16);
  gl_lds16(sB_lo,      ldsb + 32768 + d16);
  if (wid < 4) gl_lds16(sB_hi,      ldsb + 40960 + d16);
  gl_lds16(sA_lo + 32, ldsb + 16384 + d16);
  gl_lds16(sA_hi + 32, ldsb + 24576 + d16);
  gl_lds16(sB_lo + 32, ldsb + 45056 + d16);
  if (wid < 4) gl_lds16(sB_hi + 32, ldsb + 53248 + d16);
  gl_lds16(sA_lo + 64, ldsb + 57344 + 0     + d16);
  gl_lds16(sA_hi + 64, ldsb + 57344 + 8192  + d16);
  gl_lds16(sB_lo + 64, ldsb + 57344 + 32768 + d16);
  if (wid < 4) gl_lds16(sB_hi + 64, ldsb + 57344 + 40960 + d16);
  if (wid < 4) asm volatile("s_waitcnt vmcnt(8)" ::: "memory");
  else         asm volatile("s_waitcnt vmcnt(6)" ::: "memory");
  __builtin_amdgcn_s_barrier();

  for (int t = 0; t < NT; ++t) {
    const int bo = (t & 1) * 57344, bo2 = bo ^ 57344;
    const int kt1 = ((t + 1) < NT ? (t + 1) : (NT - 1)) * 64;
    const int kt2 = ((t + 2) < NT ? (t + 2) : (NT - 1)) * 64;
    // ---- phase 0
    #pragma unroll
    for (int i = 0; i < 4; ++i) av[i] = *(const s8bf*)(ldsb + bo + aoff[i]);
    #pragma unroll
    for (int nf = 0; nf < 3; ++nf) bk[nf] = *(const s8bf*)(ldsb + bo + boff[nf]);
    gl_lds16(sA_lo + kt1 + 32, ldsb + bo2 + 16384 + d16);
    gl_lds16(sA_hi + kt1 + 32, ldsb + bo2 + 24576 + d16);
    __builtin_amdgcn_s_barrier();
    asm volatile("s_waitcnt lgkmcnt(0)" ::: "memory");
    __builtin_amdgcn_s_setprio(1);
    #pragma unroll
    for (int i = 0; i < 4; ++i)
      #pragma unroll
      for (int nf = 0; nf < 3; ++nf)
        acc[i][nf] = mfma16(av[i], bk[nf], acc[i][nf]);
    __builtin_amdgcn_s_setprio(0);
    __builtin_amdgcn_s_barrier();
    // ---- phase 1
    #pragma unroll
    for (int i = 0; i < 4; ++i) av2[i] = *(const s8bf*)(ldsb + bo + aoff[4 + i]);
    gl_lds16(sB_lo + kt1 + 32, ldsb + bo2 + 45056 + d16);
    if (wid < 4) gl_lds16(sB_hi + kt1 + 32, ldsb + bo2 + 53248 + d16);
    __builtin_amdgcn_s_barrier();
    asm volatile("s_waitcnt lgkmcnt(0)" ::: "memory");
    __builtin_amdgcn_s_setprio(1);
    #pragma unroll
    for (int i = 0; i < 4; ++i)
      #pragma unroll
      for (int nf = 0; nf < 3; ++nf)
        acc[4 + i][nf] = mfma16(av2[i], bk[nf], acc[4 + i][nf]);
    __builtin_amdgcn_s_setprio(0);
    if (wid < 4) asm volatile("s_waitcnt vmcnt(8)" ::: "memory");
    else         asm volatile("s_waitcnt vmcnt(6)" ::: "memory");
    __builtin_amdgcn_s_barrier();
    // ---- phase 2
    #pragma unroll
    for (int i = 0; i < 4; ++i) av[i] = *(const s8bf*)(ldsb + bo + 16384 + aoff[i]);
    #pragma unroll
    for (int nf = 0; nf < 3; ++nf) bk[nf] = *(const s8bf*)(ldsb + bo + 12288 + boff[nf]);
    gl_lds16(sA_lo + kt2, ldsb + bo + 0    + d16);
    gl_lds16(sA_hi + kt2, ldsb + bo + 8192 + d16);
    __builtin_amdgcn_s_barrier();
    asm volatile("s_waitcnt lgkmcnt(0)" ::: "memory");
    __builtin_amdgcn_s_setprio(1);
    #pragma unroll
    for (int i = 0; i < 4; ++i)
      #pragma unroll
      for (int nf = 0; nf < 3; ++nf)
        acc[i][nf] = mfma16(av[i], bk[nf], acc[i][nf]);
    __builtin_amdgcn_s_setprio(0);
    __builtin_amdgcn_s_barrier();
    // ---- phase 3
    #pragma unroll
    for (int i = 0; i < 4; ++i) av2[i] = *(const s8bf*)(ldsb + bo + 16384 + aoff[4 + i]);
    gl_lds16(sB_lo + kt2, ldsb + bo + 32768 + d16);
    if (wid < 4) gl_lds16(sB_hi + kt2, ldsb + bo + 40960 + d16);
    __builtin_amdgcn_s_barrier();
    asm volatile("s_waitcnt lgkmcnt(0)" ::: "memory");
    __builtin_amdgcn_s_setprio(1);
    #pragma unroll
    for (int i = 0; i < 4; ++i)
      #pragma unroll
      for (int nf = 0; nf < 3; ++nf)
        acc[4 + i][nf] = mfma16(av2[i], bk[nf], acc[4 + i][nf]);
    __builtin_amdgcn_s_setprio(0);
    if (wid < 4) asm volatile("s_waitcnt vmcnt(8)" ::: "memory");
    else         asm volatile("s_waitcnt vmcnt(6)" ::: "memory");
    __builtin_amdgcn_s_barrier();
  }
  asm volatile("s_waitcnt vmcnt(0)" ::: "memory");

  const int r0 = m0 + wm * 128 + ((lane >> 4) << 2);
  const int c0 = n0 + wn * 48 + (lane & 15);
  #pragma unroll
  for (int mf = 0; mf < 8; ++mf)
    #pragma unroll
    for (int nf = 0; nf < 3; ++nf)
      #pragma unroll
      for (int v = 0; v < 4; ++v) {
        int row = r0 + mf * 16 + v, col = c0 + nf * 16;
        float val = acc[mf][nf][v];
        if (MODE == 0) ((short*)C)[(size_t)row * N + col] = f2bf(val);
        else           ((float*)C)[(size_t)row * N + col] = val;
      }
}

// ---------------- m97-style GEMM for split-K K/V projection ----------------
// MODE 5: per-slice f32 partial store (no atomics): C[z][row][col], slice stride 256*3072
template<int MODE>
__global__ __launch_bounds__(256, 2) void gemm_bt_k(
    const short* __restrict__ A, const short* __restrict__ Bt, void* __restrict__ C,
    int M, int N, int K, int kchunk)
{
  __shared__ short aT[128 * 32];
  __shared__ short bT[128 * 32];
  const int m0 = blockIdx.x * 128, n0 = blockIdx.y * 128;
  const int wid = threadIdx.x >> 6, lane = threadIdx.x & 63;
  const int wr = wid >> 1, wc = wid & 1;
  const int k_lo = blockIdx.z * kchunk, k_hi = k_lo + kchunk;
  f32x4 acc[4][4] = {};
  const int srow = wid * 32 + (lane >> 2);
  const int skoff = (lane & 3) * 8;
  const short* aG = A + (size_t)(m0 + srow) * K + skoff;
  const short* bG = Bt + (size_t)(n0 + srow) * K + skoff;
  char* aL = (char*)aT + wid * 2048;
  char* bL = (char*)bT + wid * 2048;
  const short* ap = aT + (wr * 64 + (lane & 15)) * 32 + (lane >> 4) * 8;
  const short* bp = bT + (wc * 64 + (lane & 15)) * 32 + (lane >> 4) * 8;
  for (int k0 = k_lo; k0 < k_hi; k0 += 32) {
    gl_lds16(aG + k0, aL);
    gl_lds16(aG + (size_t)16 * K + k0, aL + 1024);
    gl_lds16(bG + k0, bL);
    gl_lds16(bG + (size_t)16 * K + k0, bL + 1024);
    __syncthreads();
    s8bf af[4], bf[4];
    #pragma unroll
    for (int i = 0; i < 4; ++i) {
      af[i] = *(const s8bf*)(ap + i * 512);
      bf[i] = *(const s8bf*)(bp + i * 512);
    }
    #pragma unroll
    for (int mi = 0; mi < 4; ++mi)
      #pragma unroll
      for (int ni = 0; ni < 4; ++ni)
        acc[mi][ni] = mfma16(af[mi], bf[ni], acc[mi][ni]);
    __syncthreads();
  }
  const int r0 = m0 + wr * 64 + ((lane >> 4) << 2);
  const int c0 = n0 + wc * 64 + (lane & 15);
  float* Cf = (float*)C + (size_t)blockIdx.z * 786432;
  #pragma unroll
  for (int mi = 0; mi < 4; ++mi)
    #pragma unroll
    for (int ni = 0; ni < 4; ++ni)
      #pragma unroll
      for (int v = 0; v < 4; ++v) {
        int row = r0 + mi * 16 + v, col = c0 + ni * 16;
        Cf[(size_t)row * N + col] = acc[mi][ni][v];
      }
}

// ---------------- reduce 8 split-K slices -> bf16 K (row-major) + V^T ----------------
__global__ void kv_reduce_k(const float* __restrict__ part, short* __restrict__ kbf,
                            short* __restrict__ vtbf) {
  int t = blockIdx.x * 256 + threadIdx.x;          // t < 196608
  int row = t / 768, c4 = (t % 768) * 4;
  float4 s = {0.f, 0.f, 0.f, 0.f};
  const float* p = part + (size_t)row * 3072 + c4;
  #pragma unroll
  for (int z = 0; z < 8; ++z) {
    float4 v = *(const float4*)(p + (size_t)z * 786432);
    s.x += v.x; s.y += v.y; s.z += v.z; s.w += v.w;
  }
  if (c4 < 1536) {
    short4 o = { f2bf(s.x), f2bf(s.y), f2bf(s.z), f2bf(s.w) };
    *(short4*)(kbf + (size_t)row * 1536 + c4) = o;
  } else {
    int b = row >> 7, j = row & 127, c = c4 - 1536;
    vtbf[((size_t)(b * 1536 + c + 0)) * 128 + j] = f2bf(s.x);
    vtbf[((size_t)(b * 1536 + c + 1)) * 128 + j] = f2bf(s.y);
    vtbf[((size_t)(b * 1536 + c + 2)) * 128 + j] = f2bf(s.z);
    vtbf[((size_t)(b * 1536 + c + 3)) * 128 + j] = f2bf(s.w);
  }
}

// ---------------- fused attention for one (i-tile=128, head, batch) ----------------
// LDS 48KB: kT [0,16K), vT [16K,32K), P: waves 0/1 alias dead kT, waves 2/3 at [32K,48K)
__global__ __launch_bounds__(256, 3) void attn_k(
    const short* __restrict__ q, const short* __restrict__ kk,
    const short* __restrict__ vt, const float* __restrict__ bias,
    short* __restrict__ ao)
{
  __shared__ char sm_[49152];
  const int it = blockIdx.x, h = blockIdx.y, b = blockIdx.z;
  const int wid = threadIdx.x >> 6, lane = threadIdx.x & 63;
  const int i0 = it * 128;
  char* kT = sm_;
  char* vT = sm_ + 16384;
  char* pB = (wid < 2) ? (sm_ + wid * 8192) : (sm_ + 16384 + wid * 8192);

  #pragma unroll
  for (int c = 0; c < 4; ++c) {
    int seg = c * 256 + wid * 64 + lane;
    int j = seg >> 3, ds = seg & 7;
    int dsrc = ds ^ (j & 7);
    gl_lds16(kk + ((size_t)(b * 128 + j) * 1536 + h * 64 + dsrc * 8),
             kT + c * 4096 + wid * 1024);
  }
  #pragma unroll
  for (int c = 0; c < 4; ++c) {
    int seg = c * 256 + wid * 64 + lane;
    int d = seg >> 4, js = seg & 15;
    int jsrc = js ^ (d & 7);
    gl_lds16(vt + ((size_t)(b * 1536 + h * 64 + d) * 128 + jsrc * 8),
             vT + c * 4096 + wid * 1024);
  }

  float bcol[8];
  #pragma unroll
  for (int nj = 0; nj < 8; ++nj) bcol[nj] = bias[b * 128 + nj * 16 + (lane & 15)];

  s8bf qf[2][2];
  #pragma unroll
  for (int mi = 0; mi < 2; ++mi)
    #pragma unroll
    for (int ks = 0; ks < 2; ++ks) {
      size_t row = (size_t)(b * 4096 + i0 + wid * 32 + mi * 16 + (lane & 15));
      qf[mi][ks] = *(const s8bf*)(q + row * 1536 + h * 64 + ks * 32 + (lane >> 4) * 8);
    }
  __syncthreads();

  f32x4 s[2][8] = {};
  #pragma unroll
  for (int ks = 0; ks < 2; ++ks) {
    int kd = ks * 32 + (lane >> 4) * 8;
    #pragma unroll
    for (int nj = 0; nj < 8; ++nj) {
      int j = nj * 16 + (lane & 15);
      s8bf kb = *(const s8bf*)(kT + j * 128 + ((2 * kd) ^ ((j & 7) << 4)));
      s[0][nj] = mfma16(qf[0][ks], kb, s[0][nj]);
      s[1][nj] = mfma16(qf[1][ks], kb, s[1][nj]);
    }
  }
  __syncthreads();   // kT handoff: all waves done with K before P overlays it

  float sm[2][4];
  #pragma unroll
  for (int mi = 0; mi < 2; ++mi)
    #pragma unroll
    for (int v = 0; v < 4; ++v) {
      float mx = -1e30f;
      #pragma unroll
      for (int nj = 0; nj < 8; ++nj) {
        float sv = s[mi][nj][v] * 0.125f + bcol[nj];
        s[mi][nj][v] = sv;
        mx = fmaxf(mx, sv);
      }
      mx = fmaxf(mx, __shfl_xor(mx, 1));
      mx = fmaxf(mx, __shfl_xor(mx, 2));
      mx = fmaxf(mx, __shfl_xor(mx, 4));
      mx = fmaxf(mx, __shfl_xor(mx, 8));
      float ss = 0.f;
      #pragma unroll
      for (int nj = 0; nj < 8; ++nj) {
        float p = __expf(s[mi][nj][v] - mx);
        s[mi][nj][v] = p;
        ss += p;
      }
      ss += __shfl_xor(ss, 1);
      ss += __shfl_xor(ss, 2);
      ss += __shfl_xor(ss, 4);
      ss += __shfl_xor(ss, 8);
      sm[mi][v] = ss;
    }

  #pragma unroll
  for (int mi = 0; mi < 2; ++mi)
    #pragma unroll
    for (int v = 0; v < 4; ++v) {
      int r = mi * 16 + ((lane >> 4) << 2) + v;
      char* base = pB + r * 256;
      #pragma unroll
      for (int nj = 0; nj < 8; ++nj) {
        int j = nj * 16 + (lane & 15);
        *(short*)(base + ((2 * j) ^ ((r & 7) << 4))) = f2bf(s[mi][nj][v]);
      }
    }
  __syncthreads();

  f32x4 o_[2][4] = {};
  #pragma unroll
  for (int ks = 0; ks < 4; ++ks) {
    int j = ks * 32 + (lane >> 4) * 8;
    s8bf pa[2];
    #pragma unroll
    for (int mi = 0; mi < 2; ++mi) {
      int r = mi * 16 + (lane & 15);
      pa[mi] = *(const s8bf*)(pB + r * 256 + ((2 * j) ^ ((r & 7) << 4)));
    }
    #pragma unroll
    for (int dj = 0; dj < 4; ++dj) {
      int d = dj * 16 + (lane & 15);
      s8bf vb = *(const s8bf*)(vT + d * 256 + ((2 * j) ^ ((d & 7) << 4)));
      o_[0][dj] = mfma16(pa[0], vb, o_[0][dj]);
      o_[1][dj] = mfma16(pa[1], vb, o_[1][dj]);
    }
  }

  #pragma unroll
  for (int mi = 0; mi < 2; ++mi)
    #pragma unroll
    for (int v = 0; v < 4; ++v) {
      int r = mi * 16 + ((lane >> 4) << 2) + v;
      float is = 1.0f / sm[mi][v];
      size_t row = (size_t)(b * 4096 + i0 + wid * 32 + r);
      #pragma unroll
      for (int dj = 0; dj < 4; ++dj) {
        int d = dj * 16 + (lane & 15);
        ao[row * 1536 + h * 64 + d] = f2bf(o_[mi][dj][v] * is);
      }
    }
}

extern "C" void kernel_launch(void* const* d_in, const int* in_sizes, int n_in,
                              void* d_out, int out_size, void* d_ws, size_t ws_size,
                              hipStream_t stream) {
  const float* x   = (const float*)d_in[0];
  const float* ctx = (const float*)d_in[1];
  const void*  msk = d_in[2];
  const float* Wq  = (const float*)d_in[3];
  const float* Wk  = (const float*)d_in[4];
  const float* Wv  = (const float*)d_in[5];
  const float* Wo  = (const float*)d_in[6];
  float* out = (float*)d_out;

  const int B = 2, NI = 4096, NT = 128, C = 1536, CC = 4096, H = 24;
  const int Mq = B * NI;  // 8192
  const int Mk = B * NT;  // 256

  size_t off = 0;
  auto carve = [&](size_t bytes) -> void* {
    void* p = (char*)d_ws + off;
    off += (bytes + 255) & ~(size_t)255;
    return p;
  };
  short* xbf   = (short*)carve((size_t)Mq * C * 2);   // reused as attn-out after Q-proj
  short* ctxbf = (short*)carve((size_t)Mk * CC * 2);
  short* WqT   = (short*)carve((size_t)C * C * 2);
  short* WkT   = (short*)carve((size_t)CC * C * 2);   // WvT must follow contiguously
  short* WvT   = (short*)carve((size_t)CC * C * 2);
  short* WoT   = (short*)carve((size_t)C * C * 2);
  short* qbf   = (short*)carve((size_t)Mq * C * 2);
  short* kbf   = (short*)carve((size_t)Mk * C * 2);
  short* vtbf  = (short*)carve((size_t)Mk * C * 2);
  float* bias  = (float*)carve(256 * 4);
  short* aout  = xbf;            // alias: x dead after Q-proj
  float* part  = out;            // d_out as split-K scratch (8*3MB=25.2MB <= 50.3MB,
                                 // fully overwritten by final O-proj -> deterministic)

  // allow 112KB dynamic LDS on the pipelined GEMMs (idempotent, capture-safe)
  hipFuncSetAttribute((const void*)gemm4ph_k<0>, hipFuncAttributeMaxDynamicSharedMemorySize, 114688);
  hipFuncSetAttribute((const void*)gemm4ph_k<1>, hipFuncAttributeMaxDynamicSharedMemorySize, 114688);

  // pre-pass: casts (16B stores) + mask, then weight transposes
  cast_k<<<1665, 256, 0, stream>>>(x, ctx, msk, xbf, ctxbf, bias);
  transp_k<<<4224, 256, 0, stream>>>(Wq, Wk, Wv, Wo, WqT, WkT, WvT, WoT);

  // Q projection (4-phase GEMM, bf16 out): grid 32x8 = 256 (full CU coverage)
  gemm4ph_k<0><<<(Mq / 256) * (C / 192), 512, 114688, stream>>>(xbf, WqT, qbf, Mq, C, C);
  // K+V projections merged: split-K=8 f32 partials into d_out scratch (384 blocks), reduce
  gemm_bt_k<5><<<dim3(Mk / 128, 3072 / 128, 8), 256, 0, stream>>>(ctxbf, WkT, part, Mk, 3072, CC, 512);
  kv_reduce_k<<<768, 256, 0, stream>>>(part, kbf, vtbf);

  // fused attention
  attn_k<<<dim3(NI / 128, H, B), 256, 0, stream>>>(qbf, kbf, vtbf, bias, aout);

  // output projection (4-phase GEMM, f32 out)
  gemm4ph_k<1><<<(Mq / 256) * (C / 192), 512, 114688, stream>>>(aout, WoT, out, Mq, C, C);
}